// Round 1
// baseline (7641.318 us; speedup 1.0000x reference)
//
#include <hip/hip_runtime.h>
#include <hip/hip_cooperative_groups.h>

namespace cg = cooperative_groups;

constexpr int kH   = 1500;
constexpr int kSW  = 50;
constexpr int kSD  = 10;
constexpr int kT   = 128;
constexpr int NBLK = 250;   // 125 per direction, 12 units each
constexpr int NR53 = 53;    // 3 ctrl rows + 50 si rows

// ---------------- Precompute xW[t-independent]: xW[row][t] = W_ih[row,0:1500] @ emb[tok[t]] + b_ih[row] + b_hh[row]
__global__ __launch_bounds__(256) void k_xw(
    const float* __restrict__ Wf, const float* __restrict__ Wb,
    const float* __restrict__ bihf, const float* __restrict__ bhhf,
    const float* __restrict__ bihb, const float* __restrict__ bhhb,
    const float* __restrict__ emb, const int* __restrict__ toks,
    float* __restrict__ xW)
{
  __shared__ float Ws[16][64];
  __shared__ float Eb[64][128];
  __shared__ int tks[128];
  int b = blockIdx.x, tid = threadIdx.x;
  int row0 = b * 16;
  const float* W  = (row0 < 6000) ? Wf : Wb;
  const float* bi = (row0 < 6000) ? bihf : bihb;
  const float* bh = (row0 < 6000) ? bhhf : bhhb;
  int rbase = (row0 < 6000) ? row0 : row0 - 6000;
  int tcol = tid & 127, rg = tid >> 7;
  if (tid < 128) tks[tid] = toks[tid];
  __syncthreads();
  float acc[8] = {0.f,0.f,0.f,0.f,0.f,0.f,0.f,0.f};
  for (int k0 = 0; k0 < kH; k0 += 64) {
    int klen = kH - k0; if (klen > 64) klen = 64;
    for (int i = tid; i < 16*64; i += 256) {
      int r = i >> 6, kk = i & 63;
      Ws[r][kk] = (kk < klen) ? W[(size_t)(rbase + r)*1550 + k0 + kk] : 0.f;
    }
    for (int i = tid; i < 64*128; i += 256) {
      int kk = i >> 7, t = i & 127;
      Eb[kk][t] = (kk < klen) ? emb[(size_t)tks[t]*kH + k0 + kk] : 0.f;
    }
    __syncthreads();
    for (int kk = 0; kk < 64; ++kk) {
      float e = Eb[kk][tcol];
      #pragma unroll
      for (int r = 0; r < 8; ++r) acc[r] += Ws[rg*8 + r][kk] * e;
    }
    __syncthreads();
  }
  #pragma unroll
  for (int r = 0; r < 8; ++r) {
    int lr = rbase + rg*8 + r;
    xW[(size_t)(row0 + rg*8 + r)*kT + tcol] = acc[r] + bi[lr] + bh[lr];
  }
}

// ---------------- Bootstrap ctrl/si partial dots for t=0 from hidden0
__global__ void k_boot(const float* __restrict__ Wc, const float* __restrict__ Wsi,
                       const float* __restrict__ h0, float* __restrict__ accP)
{
  int b = blockIdx.x, lane = threadIdx.x;
  int d = (b < 125) ? 0 : 1;
  int g = d ? b - 125 : b;
  int u0 = g * 12;
  if (lane < NR53) {
    const float* Wr = (lane < 3) ? (Wc + (size_t)lane*3000) : (Wsi + (size_t)(lane-3)*3000);
    float p = 0.f;
    #pragma unroll
    for (int j = 0; j < 12; ++j) p += Wr[d*kH + u0 + j] * h0[d*kH + u0 + j];
    accP[b*NR53 + lane] = p;
  }
}

// ---------------- Persistent cooperative RNN: 128 steps, 1 grid sync per step
__global__ __launch_bounds__(256) void k_rnn(
    const float* __restrict__ Wc, const float* __restrict__ bc,
    const float* __restrict__ Wsi, const float* __restrict__ bsi,
    const float* __restrict__ Wihf, const float* __restrict__ Whhf,
    const float* __restrict__ Wihb, const float* __restrict__ Whhb,
    const float* __restrict__ xW, float* __restrict__ h_buf,
    float* __restrict__ cbuf, float* __restrict__ stk,
    float* __restrict__ accP, float* __restrict__ hs_all)
{
  cg::grid_group grid = cg::this_grid();
  int b = blockIdx.x, tid = threadIdx.x;
  int lane = tid & 63, w = tid >> 6;
  int d = (b < 125) ? 0 : 1;
  int g = d ? b - 125 : b;
  int u0 = g * 12;
  const float* Whh = d ? Whhb : Whhf;
  const float* Wih = d ? Wihb : Wihf;
  __shared__ __align__(16) float hl[kH];
  __shared__ float cs[56];      // [0..2]=ctrl (after softmax), [3..52]=si
  __shared__ float stop[kSW];
  __shared__ float gl[4][12];
  __shared__ float hnew[12];

  for (int t = 0; t < kT; ++t) {
    const float* hcur = h_buf + (t & 1) * 3000;
    float* hnxt       = h_buf + ((t + 1) & 1) * 3000;
    const float* accR = accP + (t & 1) * (NBLK * NR53);
    float* accW       = accP + ((t + 1) & 1) * (NBLK * NR53);
    const float* stOld = stk + (t & 1) * (kSD * kSW);
    float* stNew       = stk + ((t + 1) & 1) * (kSD * kSW);

    // phase 1: finish ctrl/si dots (sum 250 partials), stage h for this direction
    if (tid < NR53) {
      float s = 0.f;
      for (int i = 0; i < NBLK; ++i) s += accR[i * NR53 + tid];
      cs[tid] = (tid < 3) ? (s + bc[tid]) : tanhf(s + bsi[tid - 3]);
    }
    for (int i = tid; i < kH; i += 256) hl[i] = hcur[d * kH + i];
    __syncthreads();
    if (tid == 0) {
      float a0 = cs[0], a1 = cs[1], a2 = cs[2];
      float m = fmaxf(a0, fmaxf(a1, a2));
      float e0 = expf(a0 - m), e1 = expf(a1 - m), e2 = expf(a2 - m);
      float inv = 1.f / (e0 + e1 + e2);
      cs[0] = e0 * inv; cs[1] = e1 * inv; cs[2] = e2 * inv;
    }
    __syncthreads();
    if (tid < kSW)
      stop[tid] = cs[2] * stOld[tid] + cs[0] * cs[3 + tid] + cs[1] * stOld[kSW + tid];
    __syncthreads();

    // phase 2: gate matvec. wave w = gate w; 12 rows (units u0..u0+11)
    for (int r = 0; r < 12; ++r) {
      int lrow = w * kH + u0 + r;
      const float4* wr4 = (const float4*)(Whh + (size_t)lrow * kH);
      const float4* hl4 = (const float4*)hl;
      float a = 0.f;
      #pragma unroll
      for (int j = 0; j < 6; ++j) {
        int idx = j * 64 + lane;
        if (idx < 375) {
          float4 wv = wr4[idx], hv = hl4[idx];
          a += wv.x*hv.x + wv.y*hv.y + wv.z*hv.z + wv.w*hv.w;
        }
      }
      if (lane < kSW) a += Wih[(size_t)lrow * 1550 + kH + lane] * stop[lane];
      #pragma unroll
      for (int off = 32; off; off >>= 1) a += __shfl_xor(a, off);
      if (lane == 0) gl[w][r] = a;
    }
    __syncthreads();

    // phase 3: pointwise LSTM cell for this block's 12 units
    if (tid < 12) {
      int u = u0 + tid;
      size_t xb = ((size_t)d * 6000 + u) * kT + t;
      float gi = gl[0][tid] + xW[xb];
      float gf = gl[1][tid] + xW[xb + (size_t)kH * kT];
      float gg = gl[2][tid] + xW[xb + (size_t)2 * kH * kT];
      float go = gl[3][tid] + xW[xb + (size_t)3 * kH * kT];
      gi = 1.f / (1.f + expf(-gi));
      gf = 1.f / (1.f + expf(-gf));
      gg = tanhf(gg);
      go = 1.f / (1.f + expf(-go));
      int ci = d * kH + u;
      float cn = gf * cbuf[ci] + gi * gg;
      cbuf[ci] = cn;
      float hn = go * tanhf(cn);
      hnxt[ci] = hn;
      hs_all[(size_t)t * 3000 + ci] = hn;
      hnew[tid] = hn;
    }
    __syncthreads();

    // phase 4: this block's partial ctrl/si dots for step t+1 (over its own 12 h values)
    if (tid < NR53) {
      const float* Wr = (tid < 3) ? (Wc + (size_t)tid * 3000) : (Wsi + (size_t)(tid - 3) * 3000);
      float p = 0.f;
      #pragma unroll
      for (int j = 0; j < 12; ++j) p += Wr[d * kH + u0 + j] * hnew[j];
      accW[b * NR53 + tid] = p;
    }
    // phase 5: full stack update (block 0 only), into parity buffer for t+1
    if (b == 0) {
      for (int j = tid; j < kSD * kSW; j += 256) {
        int r = j / kSW, cc = j - r * kSW;
        float up = (r == 0) ? cs[3 + cc] : stOld[j - kSW];
        float dn = (r < kSD - 1) ? stOld[j + kSW] : 0.f;
        stNew[j] = cs[2] * stOld[j] + cs[0] * up + cs[1] * dn;
      }
    }
    grid.sync();
  }
}

// ---------------- Decoder: logits[t] = W_dec @ [h_f(t); h_b(t)] + b_dec
__global__ __launch_bounds__(256) void k_dec(
    const float* __restrict__ hs_all, const float* __restrict__ Wd,
    const float* __restrict__ bd, float* __restrict__ out)
{
  int t = blockIdx.x, tid = threadIdx.x, lane = tid & 63, w = tid >> 6;
  __shared__ __align__(16) float hv[3000];
  for (int i = tid; i < 3000; i += 256) hv[i] = hs_all[(size_t)t * 3000 + i];
  __syncthreads();
  const float4* h4 = (const float4*)hv;
  for (int r = w; r < 45; r += 4) {
    const float4* wr = (const float4*)(Wd + (size_t)r * 3000);
    float a = 0.f;
    for (int j = lane; j < 750; j += 64) {
      float4 x = wr[j], y = h4[j];
      a += x.x*y.x + x.y*y.y + x.z*y.z + x.w*y.w;
    }
    #pragma unroll
    for (int off = 32; off; off >>= 1) a += __shfl_xor(a, off);
    if (lane == 0) out[t * 45 + r] = a + bd[r];
  }
}

extern "C" void kernel_launch(void* const* d_in, const int* in_sizes, int n_in,
                              void* d_out, int out_size, void* d_ws, size_t ws_size,
                              hipStream_t stream)
{
  const int*   toks = (const int*)  d_in[0];
  const float* h0   = (const float*)d_in[1];
  const float* c0   = (const float*)d_in[2];
  const float* st0  = (const float*)d_in[3];
  const float* emb  = (const float*)d_in[4];
  const float* Wc   = (const float*)d_in[5];
  const float* bc   = (const float*)d_in[6];
  const float* Wsi  = (const float*)d_in[7];
  const float* bsi  = (const float*)d_in[8];
  const float* Wihf = (const float*)d_in[9];
  const float* Whhf = (const float*)d_in[10];
  const float* bihf = (const float*)d_in[11];
  const float* bhhf = (const float*)d_in[12];
  const float* Wihb = (const float*)d_in[13];
  const float* Whhb = (const float*)d_in[14];
  const float* bihb = (const float*)d_in[15];
  const float* bhhb = (const float*)d_in[16];
  const float* Wd   = (const float*)d_in[17];
  const float* bd   = (const float*)d_in[18];

  float* ws    = (float*)d_ws;
  float* xW    = ws;                       // 12000*128         = 1,536,000
  float* h_buf = xW + 12000*128;           // 2*3000
  float* cb    = h_buf + 6000;             // 3000
  float* stk   = cb + 3000;                // 2*500
  float* accP  = stk + 1000;               // 2*250*53          = 26,500
  float* hsall = accP + 2*NBLK*NR53;       // 128*3000          = 384,000
  (void)ws_size; (void)in_sizes; (void)n_in; (void)out_size;

  hipMemcpyAsync(h_buf, h0, 3000*sizeof(float), hipMemcpyDeviceToDevice, stream);
  hipMemcpyAsync(cb,   c0, 3000*sizeof(float), hipMemcpyDeviceToDevice, stream);
  hipMemcpyAsync(stk,  st0, 500*sizeof(float), hipMemcpyDeviceToDevice, stream);

  k_xw<<<750, 256, 0, stream>>>(Wihf, Wihb, bihf, bhhf, bihb, bhhb, emb, toks, xW);
  k_boot<<<NBLK, 64, 0, stream>>>(Wc, Wsi, h_buf, accP);

  void* args[] = { (void*)&Wc, (void*)&bc, (void*)&Wsi, (void*)&bsi,
                   (void*)&Wihf, (void*)&Whhf, (void*)&Wihb, (void*)&Whhb,
                   (void*)&xW, (void*)&h_buf, (void*)&cb, (void*)&stk,
                   (void*)&accP, (void*)&hsall };
  hipLaunchCooperativeKernel((void*)k_rnn, dim3(NBLK), dim3(256), args, 0, stream);

  k_dec<<<kT, 256, 0, stream>>>(hsall, Wd, bd, (float*)d_out);
}

// Round 2
// 5747.404 us; speedup vs baseline: 1.3295x; 1.3295x over previous
//
#include <hip/hip_runtime.h>
#include <hip/hip_cooperative_groups.h>

namespace cg = cooperative_groups;

constexpr int kH   = 1500;
constexpr int kSW  = 50;
constexpr int kSD  = 10;
constexpr int kT   = 128;
constexpr int kV   = 45;
constexpr int NBLK = 250;   // 125 per direction, 12 units each
constexpr int NR53 = 53;    // 3 ctrl rows + 50 si rows
constexpr int PSTR = 53 * 256;  // one parity plane of partials [53][256]

// ---------------- Precompute xW45[row][v] = W_ih[row,0:1500] @ emb[v] + b_ih[row] + b_hh[row]
// row in [0,12000): rows 0..5999 fwd (gate-major), 6000..11999 bwd. 750 blocks x 1024 thr, 16 rows/blk.
__global__ __launch_bounds__(1024) void k_xw45(
    const float* __restrict__ Wf, const float* __restrict__ Wb,
    const float* __restrict__ bihf, const float* __restrict__ bhhf,
    const float* __restrict__ bihb, const float* __restrict__ bhhb,
    const float* __restrict__ emb, float* __restrict__ xW45)
{
  __shared__ float Ws[16][66];
  __shared__ float Eb[64][46];
  int b = blockIdx.x, tid = threadIdx.x;
  int row0 = b * 16;
  const float* W  = (row0 < 6000) ? Wf : Wb;
  const float* bi = (row0 < 6000) ? bihf : bihb;
  const float* bh = (row0 < 6000) ? bhhf : bhhb;
  int rbase = (row0 < 6000) ? row0 : row0 - 6000;
  int rg = tid / kV, v = tid - rg * kV;   // 720 active compute threads
  bool act = (tid < 16 * kV);
  float acc = 0.f;
  for (int k0 = 0; k0 < kH; k0 += 64) {
    int klen = kH - k0; if (klen > 64) klen = 64;
    for (int i = tid; i < 16 * 64; i += 1024) {
      int r = i >> 6, kk = i & 63;
      Ws[r][kk] = (kk < klen) ? W[(size_t)(rbase + r) * 1550 + k0 + kk] : 0.f;
    }
    for (int i = tid; i < kV * 64; i += 1024) {
      int vv = i >> 6, kk = i & 63;
      Eb[kk][vv] = (kk < klen) ? emb[(size_t)vv * kH + k0 + kk] : 0.f;
    }
    __syncthreads();
    if (act) {
      #pragma unroll 8
      for (int kk = 0; kk < 64; ++kk) acc += Ws[rg][kk] * Eb[kk][v];
    }
    __syncthreads();
  }
  if (act) {
    int lr = rbase + rg;
    xW45[(size_t)(row0 + rg) * kV + v] = acc + bi[lr] + bh[lr];
  }
}

// ---------------- Bootstrap: zero partial planes, write t=0 ctrl/si partials from hidden0
__global__ void k_boot(const float* __restrict__ Wc, const float* __restrict__ Wsi,
                       const float* __restrict__ h0, float* __restrict__ accP)
{
  int b = blockIdx.x, lane = threadIdx.x;   // 256 blocks x 64 threads
  if (lane < NR53) {
    float p = 0.f;
    if (b < NBLK) {
      int d = (b < 125) ? 0 : 1;
      int g = d ? b - 125 : b;
      int u0 = g * 12;
      const float* Wr = (lane < 3) ? (Wc + (size_t)lane * 3000)
                                   : (Wsi + (size_t)(lane - 3) * 3000);
      #pragma unroll
      for (int j = 0; j < 12; ++j) p += Wr[d * kH + u0 + j] * h0[d * kH + u0 + j];
    }
    accP[lane * 256 + b] = p;          // parity 0
    accP[PSTR + lane * 256 + b] = 0.f; // parity 1
  }
}

// ---------------- Persistent cooperative RNN: 128 steps, 1 grid sync per step
__global__ __launch_bounds__(1024) void k_rnn(
    const float* __restrict__ Wc, const float* __restrict__ bc,
    const float* __restrict__ Wsi, const float* __restrict__ bsi,
    const float* __restrict__ Wihf, const float* __restrict__ Whhf,
    const float* __restrict__ Wihb, const float* __restrict__ Whhb,
    const float* __restrict__ xW45, const int* __restrict__ toks,
    float* __restrict__ h_buf, float* __restrict__ cbuf,
    float* __restrict__ stk, float* __restrict__ accP,
    float* __restrict__ hs_all)
{
  cg::grid_group grid = cg::this_grid();
  int b = blockIdx.x, tid = threadIdx.x;
  int lane = tid & 63, w = tid >> 6;      // 16 waves
  int d = (b < 125) ? 0 : 1;
  int g = d ? b - 125 : b;
  int u0 = g * 12;
  const float* Whh = d ? Whhb : Whhf;
  const float* Wih = d ? Wihb : Wihf;
  __shared__ __align__(16) float hl[kH];
  __shared__ float cs[56];      // [0..2]=raw ctrl logits, [3..52]=si (tanh'd)
  __shared__ float stop[kSW];
  __shared__ float gl[48];      // gate g, unit u -> gl[g*12+u]
  __shared__ float hnew[12];
  __shared__ int   tks[kT];

  for (int i = tid; i < kT; i += 1024) tks[i] = toks[i];
  __syncthreads();

  for (int t = 0; t < kT; ++t) {
    const float* hcur = h_buf + (t & 1) * 3000;
    float* hnxt       = h_buf + ((t + 1) & 1) * 3000;
    const float* accR = accP + (t & 1) * PSTR;
    float* accW       = accP + ((t + 1) & 1) * PSTR;
    const float* stOld = stk + (t & 1) * (kSD * kSW);
    float* stNew       = stk + ((t + 1) & 1) * (kSD * kSW);
    int tk = tks[t];

    // phase 1: stage h for this direction; reduce ctrl/si partial planes (coalesced)
    if (tid < 375)
      ((float4*)hl)[tid] = ((const float4*)(hcur + d * kH))[tid];
    for (int r = w; r < NR53; r += 16) {
      const float* pr = accR + r * 256;
      float s = pr[lane] + pr[lane + 64] + pr[lane + 128] + pr[lane + 192];
      #pragma unroll
      for (int off = 32; off; off >>= 1) s += __shfl_xor(s, off);
      if (lane == 0) cs[r] = (r < 3) ? (s + bc[r]) : tanhf(s + bsi[r - 3]);
    }
    __syncthreads();

    // stack top for this step (softmax computed redundantly per thread)
    if (tid < kSW) {
      float a0 = cs[0], a1 = cs[1], a2 = cs[2];
      float m = fmaxf(a0, fmaxf(a1, a2));
      float e0 = expf(a0 - m), e1 = expf(a1 - m), e2 = expf(a2 - m);
      float inv = 1.f / (e0 + e1 + e2);
      stop[tid] = e2 * inv * stOld[tid] + e0 * inv * cs[3 + tid] + e1 * inv * stOld[kSW + tid];
    }
    __syncthreads();

    // phase 2: gate matvec. wave w owns rows 3w..3w+2 of the 48 (=4 gates x 12 units)
    #pragma unroll
    for (int q = 0; q < 3; ++q) {
      int rr = w * 3 + q;                 // 0..47
      int gg = rr / 12, u = rr - gg * 12;
      int lrow = gg * kH + u0 + u;
      const float4* wr4 = (const float4*)(Whh + (size_t)lrow * kH);
      const float4* hl4 = (const float4*)hl;
      float a = 0.f;
      #pragma unroll
      for (int j = 0; j < 5; ++j) {
        int idx = j * 64 + lane;
        float4 wv = wr4[idx], hv = hl4[idx];
        a += wv.x * hv.x + wv.y * hv.y + wv.z * hv.z + wv.w * hv.w;
      }
      {
        int idx = 320 + lane;
        if (idx < 375) {
          float4 wv = wr4[idx], hv = hl4[idx];
          a += wv.x * hv.x + wv.y * hv.y + wv.z * hv.z + wv.w * hv.w;
        }
      }
      if (lane < kSW) a += Wih[(size_t)lrow * 1550 + kH + lane] * stop[lane];
      #pragma unroll
      for (int off = 32; off; off >>= 1) a += __shfl_xor(a, off);
      if (lane == 0) gl[rr] = a;
    }
    __syncthreads();

    // phase 3: pointwise LSTM cell for this block's 12 units
    if (tid < 12) {
      int u = u0 + tid;
      size_t xb = ((size_t)d * 6000 + u) * kV + tk;
      float gi = gl[tid]      + xW45[xb];
      float gf = gl[12 + tid] + xW45[xb + (size_t)kH * kV];
      float gg = gl[24 + tid] + xW45[xb + (size_t)2 * kH * kV];
      float go = gl[36 + tid] + xW45[xb + (size_t)3 * kH * kV];
      gi = 1.f / (1.f + expf(-gi));
      gf = 1.f / (1.f + expf(-gf));
      gg = tanhf(gg);
      go = 1.f / (1.f + expf(-go));
      int ci = d * kH + u;
      float cn = gf * cbuf[ci] + gi * gg;
      cbuf[ci] = cn;
      float hn = go * tanhf(cn);
      hnxt[ci] = hn;
      hs_all[(size_t)t * 3000 + ci] = hn;
      hnew[tid] = hn;
    }
    __syncthreads();

    // phase 4: this block's partial ctrl/si dots for step t+1
    if (tid < NR53) {
      const float* Wr = (tid < 3) ? (Wc + (size_t)tid * 3000)
                                  : (Wsi + (size_t)(tid - 3) * 3000);
      float p = 0.f;
      #pragma unroll
      for (int j = 0; j < 12; ++j) p += Wr[d * kH + u0 + j] * hnew[j];
      accW[tid * 256 + b] = p;
    }
    // phase 5: full stack update (block 0 only), softmax recomputed locally
    if (b == 0 && tid < kSD * kSW) {
      float a0 = cs[0], a1 = cs[1], a2 = cs[2];
      float m = fmaxf(a0, fmaxf(a1, a2));
      float e0 = expf(a0 - m), e1 = expf(a1 - m), e2 = expf(a2 - m);
      float inv = 1.f / (e0 + e1 + e2);
      int r = tid / kSW, cc = tid - r * kSW;
      float up = (r == 0) ? cs[3 + cc] : stOld[tid - kSW];
      float dn = (r < kSD - 1) ? stOld[tid + kSW] : 0.f;
      stNew[tid] = e2 * inv * stOld[tid] + e0 * inv * up + e1 * inv * dn;
    }
    grid.sync();
  }
}

// ---------------- Decoder: logits[t] = W_dec @ [h_f(t); h_b(t)] + b_dec
__global__ __launch_bounds__(256) void k_dec(
    const float* __restrict__ hs_all, const float* __restrict__ Wd,
    const float* __restrict__ bd, float* __restrict__ out)
{
  int t = blockIdx.x, tid = threadIdx.x, lane = tid & 63, w = tid >> 6;
  __shared__ __align__(16) float hv[3000];
  for (int i = tid; i < 3000; i += 256) hv[i] = hs_all[(size_t)t * 3000 + i];
  __syncthreads();
  const float4* h4 = (const float4*)hv;
  for (int r = w; r < kV; r += 4) {
    const float4* wr = (const float4*)(Wd + (size_t)r * 3000);
    float a = 0.f;
    for (int j = lane; j < 750; j += 64) {
      float4 x = wr[j], y = h4[j];
      a += x.x * y.x + x.y * y.y + x.z * y.z + x.w * y.w;
    }
    #pragma unroll
    for (int off = 32; off; off >>= 1) a += __shfl_xor(a, off);
    if (lane == 0) out[t * kV + r] = a + bd[r];
  }
}

extern "C" void kernel_launch(void* const* d_in, const int* in_sizes, int n_in,
                              void* d_out, int out_size, void* d_ws, size_t ws_size,
                              hipStream_t stream)
{
  const int*   toks = (const int*)  d_in[0];
  const float* h0   = (const float*)d_in[1];
  const float* c0   = (const float*)d_in[2];
  const float* st0  = (const float*)d_in[3];
  const float* emb  = (const float*)d_in[4];
  const float* Wc   = (const float*)d_in[5];
  const float* bc   = (const float*)d_in[6];
  const float* Wsi  = (const float*)d_in[7];
  const float* bsi  = (const float*)d_in[8];
  const float* Wihf = (const float*)d_in[9];
  const float* Whhf = (const float*)d_in[10];
  const float* bihf = (const float*)d_in[11];
  const float* bhhf = (const float*)d_in[12];
  const float* Wihb = (const float*)d_in[13];
  const float* Whhb = (const float*)d_in[14];
  const float* bihb = (const float*)d_in[15];
  const float* bhhb = (const float*)d_in[16];
  const float* Wd   = (const float*)d_in[17];
  const float* bd   = (const float*)d_in[18];

  float* ws    = (float*)d_ws;
  float* xW45  = ws;                        // 12000*45 = 540,000
  float* h_buf = xW45 + 12000 * kV;         // 2*3000
  float* cb    = h_buf + 6000;              // 3000
  float* stk   = cb + 3000;                 // 2*500
  float* accP  = stk + 1000;                // 2*53*256 = 27,136
  float* hsall = accP + 2 * PSTR;           // 128*3000 = 384,000
  (void)ws_size; (void)in_sizes; (void)n_in; (void)out_size;

  hipMemcpyAsync(h_buf, h0, 3000 * sizeof(float), hipMemcpyDeviceToDevice, stream);
  hipMemcpyAsync(cb,   c0, 3000 * sizeof(float), hipMemcpyDeviceToDevice, stream);
  hipMemcpyAsync(stk,  st0, 500 * sizeof(float), hipMemcpyDeviceToDevice, stream);

  k_xw45<<<750, 1024, 0, stream>>>(Wihf, Wihb, bihf, bhhf, bihb, bhhb, emb, xW45);
  k_boot<<<256, 64, 0, stream>>>(Wc, Wsi, h0, accP);

  void* args[] = { (void*)&Wc, (void*)&bc, (void*)&Wsi, (void*)&bsi,
                   (void*)&Wihf, (void*)&Whhf, (void*)&Wihb, (void*)&Whhb,
                   (void*)&xW45, (void*)&toks, (void*)&h_buf, (void*)&cb,
                   (void*)&stk, (void*)&accP, (void*)&hsall };
  hipLaunchCooperativeKernel((void*)k_rnn, dim3(NBLK), dim3(1024), args, 0, stream);

  k_dec<<<kT, 256, 0, stream>>>(hsall, Wd, bd, (float*)d_out);
}

// Round 3
// 5445.557 us; speedup vs baseline: 1.4032x; 1.0554x over previous
//
#include <hip/hip_runtime.h>
#include <hip/hip_cooperative_groups.h>

namespace cg = cooperative_groups;

constexpr int kH   = 1500;
constexpr int kSW  = 50;
constexpr int kSD  = 10;
constexpr int kT   = 128;
constexpr int kV   = 45;
constexpr int NBLK = 250;   // 125 per direction, 12 units each
constexpr int NR53 = 53;    // 3 ctrl rows + 50 si rows
constexpr int PSTR = 53 * 256;  // one parity plane of partials [53][256]

// ---------------- Precompute xW45[row][v] = W_ih[row,0:1500] @ emb[v] + b_ih[row] + b_hh[row]
__global__ __launch_bounds__(1024) void k_xw45(
    const float* __restrict__ Wf, const float* __restrict__ Wb,
    const float* __restrict__ bihf, const float* __restrict__ bhhf,
    const float* __restrict__ bihb, const float* __restrict__ bhhb,
    const float* __restrict__ emb, float* __restrict__ xW45)
{
  __shared__ float Ws[16][66];
  __shared__ float Eb[64][46];
  int b = blockIdx.x, tid = threadIdx.x;
  int row0 = b * 16;
  const float* W  = (row0 < 6000) ? Wf : Wb;
  const float* bi = (row0 < 6000) ? bihf : bihb;
  const float* bh = (row0 < 6000) ? bhhf : bhhb;
  int rbase = (row0 < 6000) ? row0 : row0 - 6000;
  int rg = tid / kV, v = tid - rg * kV;   // 720 active compute threads
  bool act = (tid < 16 * kV);
  float acc = 0.f;
  for (int k0 = 0; k0 < kH; k0 += 64) {
    int klen = kH - k0; if (klen > 64) klen = 64;
    for (int i = tid; i < 16 * 64; i += 1024) {
      int r = i >> 6, kk = i & 63;
      Ws[r][kk] = (kk < klen) ? W[(size_t)(rbase + r) * 1550 + k0 + kk] : 0.f;
    }
    for (int i = tid; i < kV * 64; i += 1024) {
      int vv = i >> 6, kk = i & 63;
      Eb[kk][vv] = (kk < klen) ? emb[(size_t)vv * kH + k0 + kk] : 0.f;
    }
    __syncthreads();
    if (act) {
      #pragma unroll 8
      for (int kk = 0; kk < 64; ++kk) acc += Ws[rg][kk] * Eb[kk][v];
    }
    __syncthreads();
  }
  if (act) {
    int lr = rbase + rg;
    xW45[(size_t)(row0 + rg) * kV + v] = acc + bi[lr] + bh[lr];
  }
}

// ---------------- Bootstrap: write t=0 ctrl/si partials from hidden0, zero parity 1
__global__ void k_boot(const float* __restrict__ Wc, const float* __restrict__ Wsi,
                       const float* __restrict__ h0, float* __restrict__ accP)
{
  int b = blockIdx.x, lane = threadIdx.x;   // 256 blocks x 64 threads
  if (lane < NR53) {
    float p = 0.f;
    if (b < NBLK) {
      int d = (b < 125) ? 0 : 1;
      int g = d ? b - 125 : b;
      int u0 = g * 12;
      const float* Wr = (lane < 3) ? (Wc + (size_t)lane * 3000)
                                   : (Wsi + (size_t)(lane - 3) * 3000);
      #pragma unroll
      for (int j = 0; j < 12; ++j) p += Wr[d * kH + u0 + j] * h0[d * kH + u0 + j];
    }
    accP[lane * 256 + b] = p;          // parity 0
    accP[PSTR + lane * 256 + b] = 0.f; // parity 1
  }
}

// ---------------- Persistent cooperative RNN, Whh register-resident
__global__ __launch_bounds__(1024, 4) void k_rnn(
    const float* __restrict__ Wc, const float* __restrict__ bc,
    const float* __restrict__ Wsi, const float* __restrict__ bsi,
    const float* __restrict__ Wihf, const float* __restrict__ Whhf,
    const float* __restrict__ Wihb, const float* __restrict__ Whhb,
    const float* __restrict__ xW45, const int* __restrict__ toks,
    float* __restrict__ h_buf, float* __restrict__ cbuf,
    float* __restrict__ stk, float* __restrict__ accP,
    float* __restrict__ hs_all)
{
  cg::grid_group grid = cg::this_grid();
  int b = blockIdx.x, tid = threadIdx.x;
  int lane = tid & 63, w = tid >> 6;      // 16 waves
  int d = (b < 125) ? 0 : 1;
  int g = d ? b - 125 : b;
  int u0 = g * 12;
  const float* Whh = d ? Whhb : Whhf;
  const float* Wih = d ? Wihb : Wihf;

  __shared__ __align__(16) float hl[1536];   // h slice, padded+zeroed to 384 float4
  __shared__ float cs[56];      // [0..2]=raw ctrl logits, [3..52]=si (tanh'd)
  __shared__ float stop[kSW];
  __shared__ float gl[48];      // gate g, unit u -> gl[g*12+u]
  __shared__ float hnew[12];
  __shared__ float Wcs[NR53 * 12];
  __shared__ int   tks[kT];

  // ---- prologue: load this wave's 3 rows of Whh into registers (18 x float4)
  int rrA = w * 3, rrB = w * 3 + 1, rrC = w * 3 + 2;
  int ggA = rrA / 12, uA = rrA - ggA * 12;
  int ggB = rrB / 12, uB = rrB - ggB * 12;
  int ggC = rrC / 12, uC = rrC - ggC * 12;
  size_t rowA = (size_t)(ggA * kH + u0 + uA);
  size_t rowB = (size_t)(ggB * kH + u0 + uB);
  size_t rowC = (size_t)(ggC * kH + u0 + uC);
  const float4* wr4A = (const float4*)(Whh + rowA * kH);
  const float4* wr4B = (const float4*)(Whh + rowB * kH);
  const float4* wr4C = (const float4*)(Whh + rowC * kH);
  float4 wA[6], wB[6], wC[6];
  const float4 f40 = make_float4(0.f, 0.f, 0.f, 0.f);
  #pragma unroll
  for (int j = 0; j < 6; ++j) {
    int idx = j * 64 + lane;
    bool ok = idx < 375;
    wA[j] = ok ? wr4A[idx] : f40;
    wB[j] = ok ? wr4B[idx] : f40;
    wC[j] = ok ? wr4C[idx] : f40;
  }
  float sA = (lane < kSW) ? Wih[rowA * 1550 + kH + lane] : 0.f;
  float sB = (lane < kSW) ? Wih[rowB * 1550 + kH + lane] : 0.f;
  float sC = (lane < kSW) ? Wih[rowC * 1550 + kH + lane] : 0.f;

  for (int i = tid; i < kT; i += 1024) tks[i] = toks[i];
  for (int i = tid; i < NR53 * 12; i += 1024) {
    int r = i / 12, j = i - r * 12;
    Wcs[i] = (r < 3) ? Wc[(size_t)r * 3000 + d * kH + u0 + j]
                     : Wsi[(size_t)(r - 3) * 3000 + d * kH + u0 + j];
  }
  if (tid >= 375 && tid < 384) ((float4*)hl)[tid] = f40;  // zero pad tail once
  __syncthreads();

  const float4* hl4 = (const float4*)hl;

  for (int t = 0; t < kT; ++t) {
    const float* hcur = h_buf + (t & 1) * 3000;
    float* hnxt       = h_buf + ((t + 1) & 1) * 3000;
    const float* accR = accP + (t & 1) * PSTR;
    float* accW       = accP + ((t + 1) & 1) * PSTR;
    const float* stOld = stk + (t & 1) * (kSD * kSW);
    float* stNew       = stk + ((t + 1) & 1) * (kSD * kSW);
    int tk = tks[t];

    // phase 1: stage h; prefetch xW/c for this block's 12 units; reduce partial planes
    if (tid < 375)
      ((float4*)hl)[tid] = ((const float4*)(hcur + d * kH))[tid];
    float xg0, xg1, xg2, xg3, cold;
    if (tid < 12) {
      size_t xb = ((size_t)d * 6000 + u0 + tid) * kV + tk;
      xg0 = xW45[xb];
      xg1 = xW45[xb + (size_t)kH * kV];
      xg2 = xW45[xb + (size_t)2 * kH * kV];
      xg3 = xW45[xb + (size_t)3 * kH * kV];
      cold = cbuf[d * kH + u0 + tid];
    }
    for (int r = w; r < NR53; r += 16) {
      const float* pr = accR + r * 256;
      float s = pr[lane] + pr[lane + 64] + pr[lane + 128] + pr[lane + 192];
      #pragma unroll
      for (int off = 32; off; off >>= 1) s += __shfl_xor(s, off);
      if (lane == 0) cs[r] = (r < 3) ? (s + bc[r]) : tanhf(s + bsi[r - 3]);
    }
    __syncthreads();

    // stack top for this step (softmax recomputed by the 50 threads)
    if (tid < kSW) {
      float a0 = cs[0], a1 = cs[1], a2 = cs[2];
      float m = fmaxf(a0, fmaxf(a1, a2));
      float e0 = expf(a0 - m), e1 = expf(a1 - m), e2 = expf(a2 - m);
      float inv = 1.f / (e0 + e1 + e2);
      stop[tid] = e2 * inv * stOld[tid] + e0 * inv * cs[3 + tid] + e1 * inv * stOld[kSW + tid];
    }
    __syncthreads();

    // phase 2: register-resident matvec; rows rrA/rrB/rrC of 48
    float a0 = 0.f, a1 = 0.f, a2 = 0.f;
    #pragma unroll
    for (int j = 0; j < 6; ++j) {
      float4 hv = hl4[j * 64 + lane];
      a0 += wA[j].x * hv.x + wA[j].y * hv.y + wA[j].z * hv.z + wA[j].w * hv.w;
      a1 += wB[j].x * hv.x + wB[j].y * hv.y + wB[j].z * hv.z + wB[j].w * hv.w;
      a2 += wC[j].x * hv.x + wC[j].y * hv.y + wC[j].z * hv.z + wC[j].w * hv.w;
    }
    {
      float sv = (lane < kSW) ? stop[lane] : 0.f;
      a0 += sA * sv; a1 += sB * sv; a2 += sC * sv;
    }
    #pragma unroll
    for (int off = 32; off; off >>= 1) {
      a0 += __shfl_xor(a0, off);
      a1 += __shfl_xor(a1, off);
      a2 += __shfl_xor(a2, off);
    }
    if (lane == 0) { gl[rrA] = a0; gl[rrB] = a1; gl[rrC] = a2; }
    __syncthreads();

    // phase 3: pointwise LSTM cell for this block's 12 units
    if (tid < 12) {
      float gi = gl[tid]      + xg0;
      float gf = gl[12 + tid] + xg1;
      float gg = gl[24 + tid] + xg2;
      float go = gl[36 + tid] + xg3;
      gi = 1.f / (1.f + expf(-gi));
      gf = 1.f / (1.f + expf(-gf));
      gg = tanhf(gg);
      go = 1.f / (1.f + expf(-go));
      int ci = d * kH + u0 + tid;
      float cn = gf * cold + gi * gg;
      cbuf[ci] = cn;
      float hn = go * tanhf(cn);
      hnxt[ci] = hn;
      hs_all[(size_t)t * 3000 + ci] = hn;
      hnew[tid] = hn;
    }
    __syncthreads();

    // phase 4: this block's partial ctrl/si dots for step t+1
    if (tid < NR53) {
      float p = 0.f;
      #pragma unroll
      for (int j = 0; j < 12; ++j) p += Wcs[tid * 12 + j] * hnew[j];
      accW[tid * 256 + b] = p;
    }
    // phase 5: full stack update (block 0 only)
    if (b == 0 && tid < kSD * kSW) {
      float a0s = cs[0], a1s = cs[1], a2s = cs[2];
      float m = fmaxf(a0s, fmaxf(a1s, a2s));
      float e0 = expf(a0s - m), e1 = expf(a1s - m), e2 = expf(a2s - m);
      float inv = 1.f / (e0 + e1 + e2);
      int r = tid / kSW, cc = tid - r * kSW;
      float up = (r == 0) ? cs[3 + cc] : stOld[tid - kSW];
      float dn = (r < kSD - 1) ? stOld[tid + kSW] : 0.f;
      stNew[tid] = e2 * inv * stOld[tid] + e0 * inv * up + e1 * inv * dn;
    }
    grid.sync();
  }
}

// ---------------- Decoder: logits[t] = W_dec @ [h_f(t); h_b(t)] + b_dec
__global__ __launch_bounds__(256) void k_dec(
    const float* __restrict__ hs_all, const float* __restrict__ Wd,
    const float* __restrict__ bd, float* __restrict__ out)
{
  int t = blockIdx.x, tid = threadIdx.x, lane = tid & 63, w = tid >> 6;
  __shared__ __align__(16) float hv[3000];
  for (int i = tid; i < 3000; i += 256) hv[i] = hs_all[(size_t)t * 3000 + i];
  __syncthreads();
  const float4* h4 = (const float4*)hv;
  for (int r = w; r < kV; r += 4) {
    const float4* wr = (const float4*)(Wd + (size_t)r * 3000);
    float a = 0.f;
    for (int j = lane; j < 750; j += 64) {
      float4 x = wr[j], y = h4[j];
      a += x.x * y.x + x.y * y.y + x.z * y.z + x.w * y.w;
    }
    #pragma unroll
    for (int off = 32; off; off >>= 1) a += __shfl_xor(a, off);
    if (lane == 0) out[t * kV + r] = a + bd[r];
  }
}

extern "C" void kernel_launch(void* const* d_in, const int* in_sizes, int n_in,
                              void* d_out, int out_size, void* d_ws, size_t ws_size,
                              hipStream_t stream)
{
  const int*   toks = (const int*)  d_in[0];
  const float* h0   = (const float*)d_in[1];
  const float* c0   = (const float*)d_in[2];
  const float* st0  = (const float*)d_in[3];
  const float* emb  = (const float*)d_in[4];
  const float* Wc   = (const float*)d_in[5];
  const float* bc   = (const float*)d_in[6];
  const float* Wsi  = (const float*)d_in[7];
  const float* bsi  = (const float*)d_in[8];
  const float* Wihf = (const float*)d_in[9];
  const float* Whhf = (const float*)d_in[10];
  const float* bihf = (const float*)d_in[11];
  const float* bhhf = (const float*)d_in[12];
  const float* Wihb = (const float*)d_in[13];
  const float* Whhb = (const float*)d_in[14];
  const float* bihb = (const float*)d_in[15];
  const float* bhhb = (const float*)d_in[16];
  const float* Wd   = (const float*)d_in[17];
  const float* bd   = (const float*)d_in[18];

  float* ws    = (float*)d_ws;
  float* xW45  = ws;                        // 12000*45 = 540,000
  float* h_buf = xW45 + 12000 * kV;         // 2*3000
  float* cb    = h_buf + 6000;              // 3000
  float* stk   = cb + 3000;                 // 2*500
  float* accP  = stk + 1000;                // 2*53*256 = 27,136
  float* hsall = accP + 2 * PSTR;           // 128*3000 = 384,000
  (void)ws_size; (void)in_sizes; (void)n_in; (void)out_size;

  hipMemcpyAsync(h_buf, h0, 3000 * sizeof(float), hipMemcpyDeviceToDevice, stream);
  hipMemcpyAsync(cb,   c0, 3000 * sizeof(float), hipMemcpyDeviceToDevice, stream);
  hipMemcpyAsync(stk,  st0, 500 * sizeof(float), hipMemcpyDeviceToDevice, stream);

  k_xw45<<<750, 1024, 0, stream>>>(Wihf, Wihb, bihf, bhhf, bihb, bhhb, emb, xW45);
  k_boot<<<256, 64, 0, stream>>>(Wc, Wsi, h0, accP);

  void* args[] = { (void*)&Wc, (void*)&bc, (void*)&Wsi, (void*)&bsi,
                   (void*)&Wihf, (void*)&Whhf, (void*)&Wihb, (void*)&Whhb,
                   (void*)&xW45, (void*)&toks, (void*)&h_buf, (void*)&cb,
                   (void*)&stk, (void*)&accP, (void*)&hsall };
  hipLaunchCooperativeKernel((void*)k_rnn, dim3(NBLK), dim3(1024), args, 0, stream);

  k_dec<<<kT, 256, 0, stream>>>(hsall, Wd, bd, (float*)d_out);
}

// Round 4
// 1784.124 us; speedup vs baseline: 4.2830x; 3.0522x over previous
//
#include <hip/hip_runtime.h>

constexpr int kH   = 1500;
constexpr int kSW  = 50;
constexpr int kSD  = 10;
constexpr int kT   = 128;
constexpr int kV   = 45;
constexpr int NBLK = 250;   // 125 per direction, 12 units each
constexpr int NR53 = 53;    // 3 ctrl rows + 50 si rows
constexpr int PSTR = 53 * 256;  // one parity plane of partials [53][256]

#define SCOPE_AGENT __HIP_MEMORY_SCOPE_AGENT

__device__ __forceinline__ float cload(const float* p) {
  return __hip_atomic_load(p, __ATOMIC_RELAXED, SCOPE_AGENT);
}
__device__ __forceinline__ void cstore(float* p, float v) {
  __hip_atomic_store(p, v, __ATOMIC_RELAXED, SCOPE_AGENT);
}
__device__ __forceinline__ int icload(const int* p) {
  return __hip_atomic_load(p, __ATOMIC_RELAXED, SCOPE_AGENT);
}

// Fence-free grid barrier. Monotonic counters; all cross-block data moves via
// sc1 (agent-scope) ops, so no cache maintenance is required. __syncthreads()
// before arrival drains vmcnt(0) -> all this block's coherent stores are at the
// coherence point before the arrival atomic lands.
__device__ __forceinline__ void gbar(int* bar, int b, int tid, int tgt) {
  __syncthreads();
  if (tid == 0) {
    int* leaf = bar + 32 + (b / 10) * 32;   // 25 leaves x 10 blocks
    int* flag = bar + 1024 + (b & 7) * 64;  // 8 mirrored generation flags
    int my = __hip_atomic_fetch_add(leaf, 1, __ATOMIC_RELAXED, SCOPE_AGENT);
    if (my == 10 * tgt - 1) {
      int r = __hip_atomic_fetch_add(bar, 1, __ATOMIC_RELAXED, SCOPE_AGENT);
      if (r == 25 * tgt - 1) {
        #pragma unroll
        for (int i = 0; i < 8; ++i)
          __hip_atomic_store(bar + 1024 + i * 64, tgt, __ATOMIC_RELAXED, SCOPE_AGENT);
      }
    }
    while (icload(flag) < tgt) __builtin_amdgcn_s_sleep(1);
  }
  __syncthreads();
}

// ---------------- Precompute xW45[row][v] = W_ih[row,0:1500] @ emb[v] + b_ih[row] + b_hh[row]
__global__ __launch_bounds__(1024) void k_xw45(
    const float* __restrict__ Wf, const float* __restrict__ Wb,
    const float* __restrict__ bihf, const float* __restrict__ bhhf,
    const float* __restrict__ bihb, const float* __restrict__ bhhb,
    const float* __restrict__ emb, float* __restrict__ xW45)
{
  __shared__ float Ws[16][66];
  __shared__ float Eb[64][46];
  int b = blockIdx.x, tid = threadIdx.x;
  int row0 = b * 16;
  const float* W  = (row0 < 6000) ? Wf : Wb;
  const float* bi = (row0 < 6000) ? bihf : bihb;
  const float* bh = (row0 < 6000) ? bhhf : bhhb;
  int rbase = (row0 < 6000) ? row0 : row0 - 6000;
  int rg = tid / kV, v = tid - rg * kV;   // 720 active compute threads
  bool act = (tid < 16 * kV);
  float acc = 0.f;
  for (int k0 = 0; k0 < kH; k0 += 64) {
    int klen = kH - k0; if (klen > 64) klen = 64;
    for (int i = tid; i < 16 * 64; i += 1024) {
      int r = i >> 6, kk = i & 63;
      Ws[r][kk] = (kk < klen) ? W[(size_t)(rbase + r) * 1550 + k0 + kk] : 0.f;
    }
    for (int i = tid; i < kV * 64; i += 1024) {
      int vv = i >> 6, kk = i & 63;
      Eb[kk][vv] = (kk < klen) ? emb[(size_t)vv * kH + k0 + kk] : 0.f;
    }
    __syncthreads();
    if (act) {
      #pragma unroll 8
      for (int kk = 0; kk < 64; ++kk) acc += Ws[rg][kk] * Eb[kk][v];
    }
    __syncthreads();
  }
  if (act) {
    int lr = rbase + rg;
    xW45[(size_t)(row0 + rg) * kV + v] = acc + bi[lr] + bh[lr];
  }
}

// ---------------- Bootstrap: t=0 ctrl/si partials from hidden0; zero parity 1; zero barrier
__global__ void k_boot(const float* __restrict__ Wc, const float* __restrict__ Wsi,
                       const float* __restrict__ h0, float* __restrict__ accP,
                       int* __restrict__ bar)
{
  int b = blockIdx.x, lane = threadIdx.x;   // 256 blocks x 64 threads
  if (b == 0) {
    for (int i = lane; i < 2048; i += 64) bar[i] = 0;
  }
  if (lane < NR53) {
    float p = 0.f;
    if (b < NBLK) {
      int d = (b < 125) ? 0 : 1;
      int g = d ? b - 125 : b;
      int u0 = g * 12;
      const float* Wr = (lane < 3) ? (Wc + (size_t)lane * 3000)
                                   : (Wsi + (size_t)(lane - 3) * 3000);
      #pragma unroll
      for (int j = 0; j < 12; ++j) p += Wr[d * kH + u0 + j] * h0[d * kH + u0 + j];
    }
    accP[lane * 256 + b] = p;          // parity 0
    accP[PSTR + lane * 256 + b] = 0.f; // parity 1
  }
}

// ---------------- Persistent RNN, Whh register-resident, custom fence-free barrier
__global__ __launch_bounds__(1024, 4) void k_rnn(
    const float* __restrict__ Wc, const float* __restrict__ bc,
    const float* __restrict__ Wsi, const float* __restrict__ bsi,
    const float* __restrict__ Wihf, const float* __restrict__ Whhf,
    const float* __restrict__ Wihb, const float* __restrict__ Whhb,
    const float* __restrict__ xW45, const int* __restrict__ toks,
    float* __restrict__ h_buf, float* __restrict__ cbuf,
    float* __restrict__ stk, float* __restrict__ accP,
    float* __restrict__ hs_all, int* __restrict__ bar)
{
  int b = blockIdx.x, tid = threadIdx.x;
  int lane = tid & 63, w = tid >> 6;      // 16 waves
  int d = (b < 125) ? 0 : 1;
  int g = d ? b - 125 : b;
  int u0 = g * 12;
  const float* Whh = d ? Whhb : Whhf;
  const float* Wih = d ? Wihb : Wihf;

  __shared__ __align__(16) float hl[1536];   // h slice, padded+zeroed to 384 float4
  __shared__ float stOldL[512];  // stack rows (all blocks: rows 0-1; block0: all 10)
  __shared__ float cs[56];       // [0..2]=raw ctrl logits, [3..52]=si (tanh'd)
  __shared__ float gl[48];       // gate g, unit u -> gl[g*12+u]
  __shared__ float hnew[12];
  __shared__ float Wcs[NR53 * 12];
  __shared__ int   tks[kT];

  // ---- prologue: this wave's 3 rows of Whh into registers (18 x float4), kept live via asm
  int rrA = w * 3, rrB = w * 3 + 1, rrC = w * 3 + 2;
  int ggA = rrA / 12, uA = rrA - ggA * 12;
  int ggB = rrB / 12, uB = rrB - ggB * 12;
  int ggC = rrC / 12, uC = rrC - ggC * 12;
  size_t rowA = (size_t)(ggA * kH + u0 + uA);
  size_t rowB = (size_t)(ggB * kH + u0 + uB);
  size_t rowC = (size_t)(ggC * kH + u0 + uC);
  const float4* wr4A = (const float4*)(Whh + rowA * kH);
  const float4* wr4B = (const float4*)(Whh + rowB * kH);
  const float4* wr4C = (const float4*)(Whh + rowC * kH);
  float4 wA[6], wB[6], wC[6];
  const float4 f40 = make_float4(0.f, 0.f, 0.f, 0.f);
  #pragma unroll
  for (int j = 0; j < 6; ++j) {
    int idx = j * 64 + lane;
    bool ok = idx < 375;
    wA[j] = ok ? wr4A[idx] : f40;
    wB[j] = ok ? wr4B[idx] : f40;
    wC[j] = ok ? wr4C[idx] : f40;
  }
  float sA = (lane < kSW) ? Wih[rowA * 1550 + kH + lane] : 0.f;
  float sB = (lane < kSW) ? Wih[rowB * 1550 + kH + lane] : 0.f;
  float sC = (lane < kSW) ? Wih[rowC * 1550 + kH + lane] : 0.f;
  // Opaque keep-alive: forbid rematerialization/sinking of the weight loads.
  #pragma unroll
  for (int j = 0; j < 6; ++j) {
    asm volatile("" : "+v"(wA[j].x), "+v"(wA[j].y), "+v"(wA[j].z), "+v"(wA[j].w));
    asm volatile("" : "+v"(wB[j].x), "+v"(wB[j].y), "+v"(wB[j].z), "+v"(wB[j].w));
    asm volatile("" : "+v"(wC[j].x), "+v"(wC[j].y), "+v"(wC[j].z), "+v"(wC[j].w));
  }
  asm volatile("" : "+v"(sA), "+v"(sB), "+v"(sC));

  for (int i = tid; i < kT; i += 1024) tks[i] = toks[i];
  for (int i = tid; i < NR53 * 12; i += 1024) {
    int r = i / 12, j = i - r * 12;
    Wcs[i] = (r < 3) ? Wc[(size_t)r * 3000 + d * kH + u0 + j]
                     : Wsi[(size_t)(r - 3) * 3000 + d * kH + u0 + j];
  }
  for (int i = 1500 + tid; i < 1536; i += 1024) hl[i] = 0.f;  // zero pad tail once
  __syncthreads();

  const float4* hl4 = (const float4*)hl;

  for (int t = 0; t < kT; ++t) {
    const float* hcur  = h_buf + (t & 1) * 3000;
    float* hnxt        = h_buf + ((t + 1) & 1) * 3000;
    const float* accR  = accP + (t & 1) * PSTR;
    float* accW        = accP + ((t + 1) & 1) * PSTR;
    const float* stOld = stk + (t & 1) * (kSD * kSW);
    float* stNew       = stk + ((t + 1) & 1) * (kSD * kSW);
    int tk = tks[t];

    // phase 1: coherent-stage h + stack rows; prefetch xW/c; reduce partial planes
    for (int i = tid; i < kH; i += 1024) hl[i] = cload(hcur + d * kH + i);
    {
      int lim = (b == 0) ? (kSD * kSW) : (2 * kSW);
      for (int i = tid; i < lim; i += 1024) stOldL[i] = cload(stOld + i);
    }
    float xg0, xg1, xg2, xg3, cold;
    if (tid < 12) {
      size_t xb = ((size_t)d * 6000 + u0 + tid) * kV + tk;
      xg0 = xW45[xb];
      xg1 = xW45[xb + (size_t)kH * kV];
      xg2 = xW45[xb + (size_t)2 * kH * kV];
      xg3 = xW45[xb + (size_t)3 * kH * kV];
      cold = cbuf[d * kH + u0 + tid];
    }
    for (int r = w; r < NR53; r += 16) {
      const float* pr = accR + r * 256;
      float s = cload(pr + lane) + cload(pr + lane + 64) +
                cload(pr + lane + 128) + cload(pr + lane + 192);
      #pragma unroll
      for (int off = 32; off; off >>= 1) s += __shfl_xor(s, off);
      if (lane == 0) cs[r] = (r < 3) ? (s + bc[r]) : tanhf(s + bsi[r - 3]);
    }
    __syncthreads();

    // phase 2: per-wave stack-top value, then register-resident matvec
    float sv = 0.f;
    {
      float a0s = cs[0], a1s = cs[1], a2s = cs[2];
      float m = fmaxf(a0s, fmaxf(a1s, a2s));
      float e0 = expf(a0s - m), e1 = expf(a1s - m), e2 = expf(a2s - m);
      float inv = 1.f / (e0 + e1 + e2);
      if (lane < kSW)
        sv = e2 * inv * stOldL[lane] + e0 * inv * cs[3 + lane] + e1 * inv * stOldL[kSW + lane];
    }
    float a0 = 0.f, a1 = 0.f, a2 = 0.f;
    #pragma unroll
    for (int j = 0; j < 6; ++j) {
      float4 hv = hl4[j * 64 + lane];
      a0 += wA[j].x * hv.x + wA[j].y * hv.y + wA[j].z * hv.z + wA[j].w * hv.w;
      a1 += wB[j].x * hv.x + wB[j].y * hv.y + wB[j].z * hv.z + wB[j].w * hv.w;
      a2 += wC[j].x * hv.x + wC[j].y * hv.y + wC[j].z * hv.z + wC[j].w * hv.w;
    }
    a0 += sA * sv; a1 += sB * sv; a2 += sC * sv;
    #pragma unroll
    for (int off = 32; off; off >>= 1) {
      a0 += __shfl_xor(a0, off);
      a1 += __shfl_xor(a1, off);
      a2 += __shfl_xor(a2, off);
    }
    if (lane == 0) { gl[rrA] = a0; gl[rrB] = a1; gl[rrC] = a2; }

    // phase 5 (overlapped): block 0 computes next stack state from LDS copy
    if (b == 0 && tid < kSD * kSW) {
      float a0s = cs[0], a1s = cs[1], a2s = cs[2];
      float m = fmaxf(a0s, fmaxf(a1s, a2s));
      float e0 = expf(a0s - m), e1 = expf(a1s - m), e2 = expf(a2s - m);
      float inv = 1.f / (e0 + e1 + e2);
      int r = tid / kSW, cc = tid - r * kSW;
      float up = (r == 0) ? cs[3 + cc] : stOldL[tid - kSW];
      float dn = (r < kSD - 1) ? stOldL[tid + kSW] : 0.f;
      cstore(&stNew[tid], e2 * inv * stOldL[tid] + e0 * inv * up + e1 * inv * dn);
    }
    __syncthreads();

    // phase 3: pointwise LSTM cell for this block's 12 units
    if (tid < 12) {
      float gi = gl[tid]      + xg0;
      float gf = gl[12 + tid] + xg1;
      float gg = gl[24 + tid] + xg2;
      float go = gl[36 + tid] + xg3;
      gi = 1.f / (1.f + expf(-gi));
      gf = 1.f / (1.f + expf(-gf));
      gg = tanhf(gg);
      go = 1.f / (1.f + expf(-go));
      int ci = d * kH + u0 + tid;
      float cn = gf * cold + gi * gg;
      cbuf[ci] = cn;                       // block-private, plain
      float hn = go * tanhf(cn);
      cstore(&hnxt[ci], hn);               // cross-block, coherent
      hs_all[(size_t)t * 3000 + ci] = hn;  // cross-kernel only, plain
      hnew[tid] = hn;
    }
    __syncthreads();

    // phase 4: this block's partial ctrl/si dots for step t+1
    if (tid < NR53) {
      float p = 0.f;
      #pragma unroll
      for (int j = 0; j < 12; ++j) p += Wcs[tid * 12 + j] * hnew[j];
      cstore(&accW[tid * 256 + b], p);
    }
    if (t < kT - 1) gbar(bar, b, tid, t + 1);
  }
}

// ---------------- Decoder: logits[t] = W_dec @ [h_f(t); h_b(t)] + b_dec
__global__ __launch_bounds__(256) void k_dec(
    const float* __restrict__ hs_all, const float* __restrict__ Wd,
    const float* __restrict__ bd, float* __restrict__ out)
{
  int t = blockIdx.x, tid = threadIdx.x, lane = tid & 63, w = tid >> 6;
  __shared__ __align__(16) float hv[3000];
  for (int i = tid; i < 3000; i += 256) hv[i] = hs_all[(size_t)t * 3000 + i];
  __syncthreads();
  const float4* h4 = (const float4*)hv;
  for (int r = w; r < kV; r += 4) {
    const float4* wr = (const float4*)(Wd + (size_t)r * 3000);
    float a = 0.f;
    for (int j = lane; j < 750; j += 64) {
      float4 x = wr[j], y = h4[j];
      a += x.x * y.x + x.y * y.y + x.z * y.z + x.w * y.w;
    }
    #pragma unroll
    for (int off = 32; off; off >>= 1) a += __shfl_xor(a, off);
    if (lane == 0) out[t * kV + r] = a + bd[r];
  }
}

extern "C" void kernel_launch(void* const* d_in, const int* in_sizes, int n_in,
                              void* d_out, int out_size, void* d_ws, size_t ws_size,
                              hipStream_t stream)
{
  const int*   toks = (const int*)  d_in[0];
  const float* h0   = (const float*)d_in[1];
  const float* c0   = (const float*)d_in[2];
  const float* st0  = (const float*)d_in[3];
  const float* emb  = (const float*)d_in[4];
  const float* Wc   = (const float*)d_in[5];
  const float* bc   = (const float*)d_in[6];
  const float* Wsi  = (const float*)d_in[7];
  const float* bsi  = (const float*)d_in[8];
  const float* Wihf = (const float*)d_in[9];
  const float* Whhf = (const float*)d_in[10];
  const float* bihf = (const float*)d_in[11];
  const float* bhhf = (const float*)d_in[12];
  const float* Wihb = (const float*)d_in[13];
  const float* Whhb = (const float*)d_in[14];
  const float* bihb = (const float*)d_in[15];
  const float* bhhb = (const float*)d_in[16];
  const float* Wd   = (const float*)d_in[17];
  const float* bd   = (const float*)d_in[18];

  float* ws    = (float*)d_ws;
  float* xW45  = ws;                        // 12000*45 = 540,000
  float* h_buf = xW45 + 12000 * kV;         // 2*3000
  float* cb    = h_buf + 6000;              // 3000
  float* stk   = cb + 3000;                 // 2*500
  float* accP  = stk + 1000;                // 2*53*256 = 27,136
  float* hsall = accP + 2 * PSTR;           // 128*3000 = 384,000
  int*   bar   = (int*)(hsall + (size_t)kT * 3000);  // 2048 ints
  (void)ws_size; (void)in_sizes; (void)n_in; (void)out_size;

  hipMemcpyAsync(h_buf, h0, 3000 * sizeof(float), hipMemcpyDeviceToDevice, stream);
  hipMemcpyAsync(cb,   c0, 3000 * sizeof(float), hipMemcpyDeviceToDevice, stream);
  hipMemcpyAsync(stk,  st0, 500 * sizeof(float), hipMemcpyDeviceToDevice, stream);

  k_xw45<<<750, 1024, 0, stream>>>(Wihf, Wihb, bihf, bhhf, bihb, bhhb, emb, xW45);
  k_boot<<<256, 64, 0, stream>>>(Wc, Wsi, h0, accP, bar);

  k_rnn<<<NBLK, 1024, 0, stream>>>(Wc, bc, Wsi, bsi, Wihf, Whhf, Wihb, Whhb,
                                   xW45, toks, h_buf, cb, stk, accP, hsall, bar);

  k_dec<<<kT, 256, 0, stream>>>(hsall, Wd, bd, (float*)d_out);
}